// Round 7
// baseline (300.305 us; speedup 1.0000x reference)
//
#include <hip/hip_runtime.h>

#define D_MODEL 64
#define SEQ     4096
#define BATCH   256
#define NSIG    128
#define CSTEP   32
#define NCHUNK  (SEQ / CSTEP)   // 128
#define NGRP    (SEQ / 8)       // 512 groups of 8 steps

constexpr float PHI_F     = 1.61803398874989484820f;
constexpr float TWO_PI_F  = 6.28318530717958647692f;
constexpr float INV2PI_F  = 0.15915494309189533577f;
constexpr float MAGIC_F   = 3072.0f;            // quantizes at ulp 2^-12 = 1 LUT bin
constexpr float FLOORB_F  = 0.0001220703125f;   // 2^-13: RNE(y - 2^-13) at 2^-12 grid == floor

// One block (256 threads = 4 waves) per TWO batch rows (128 blocks).
// wave 0: two interleaved serial scan chains (rows 2*blk, 2*blk+1), lane = dim.
//   Chain per step: fma -> +-3072 (magic floor-quantize) -> add -> cos/sin.
// waves 1-3: loaders — gather emb rows for both batch rows, pre-transform to
//   (r4, C) in revolution units, stage into 4-slot LDS ring 2 chunks ahead.
// LDS layout: TWO float2 planes (8 B lane stride — measured conflict-free in
// R3-R5); R6's [lane][4] 16 B-stride layout caused 8-way conflicts (4.3M).
__global__ __launch_bounds__(256, 1)
void rin_scan_kernel(const int* __restrict__ ids,
                     const float* __restrict__ emb,   // (50257, 128) f32
                     const float* __restrict__ pw,    // (128, 128) f32
                     const float* __restrict__ pb,    // (128,) f32
                     float* __restrict__ out)         // (256, 128) f32
{
  __shared__ float2 ring_a[4][CSTEP][D_MODEL];   // 64 KB: row 0 (r4, C)
  __shared__ float2 ring_b[4][CSTEP][D_MODEL];   // 64 KB: row 1 (r4, C)
  __shared__ float  lds_h[2][2 * D_MODEL];

  const int tid  = threadIdx.x;
  const int wave = tid >> 6;
  const int lane = tid & 63;
  const int blk  = blockIdx.x;                   // rows 2*blk, 2*blk+1

  float2 hr2 = make_float2(0.0f, 0.0f);
  float2 hi2 = make_float2(0.0f, 0.0f);

  // ---- loader: stage chunk c (32 steps x 2 rows = 64 units) into slot s ----
  auto stage = [&](int c, int s) {
    float wv[22], bv[22];
    #pragma unroll
    for (int k = 0; k < 22; ++k) {
      int u = 3 * k + (wave - 1); u = (u < 2 * CSTEP) ? u : (2 * CSTEP - 1);
      int i = u >> 1, r = u & 1;
      int t = c * CSTEP + i;
      int id = ids[(2 * blk + r) * SEQ + t];     // wave-uniform -> scalar load
      const float* row = emb + (size_t)id * (2 * D_MODEL);
      wv[k] = row[lane];
      bv[k] = row[D_MODEL + lane];
    }
    #pragma unroll
    for (int k = 0; k < 22; ++k) {
      int u = 3 * k + (wave - 1); u = (u < 2 * CSTEP) ? u : (2 * CSTEP - 1);
      int i = u >> 1, r = u & 1;
      int t = c * CSTEP + i;
      float pf  = (float)t * PHI_F;
      float n   = floorf(pf * INV2PI_F);
      float tp  = fmaf(-n, TWO_PI_F, pf);        // fmod(t*PHI, 2pi)
      float tpr = tp * INV2PI_F;                 // revolutions
      float r4  = __builtin_amdgcn_rcpf(1.0f + fabsf(wv[k])) * INV2PI_F;
      float C   = fmaf(bv[k], INV2PI_F, tpr) - FLOORB_F;
      float2 val = make_float2(r4, C);
      if (r == 0) ring_a[s][i][lane] = val;      // r is wave-uniform
      else        ring_b[s][i][lane] = val;
    }
  };

  // ---- compute helpers (wave 0); g = global group index 0..NGRP-1 ----
  auto P = [&](int g, float2* da, float2* db) {
    int gg = (g < NGRP) ? g : (NGRP - 1);
    int sl = (gg >> 2) & 3, st = (gg & 3) * 8;
    #pragma unroll
    for (int u = 0; u < 8; ++u) {
      da[u] = ring_a[sl][st + u][lane];
      db[u] = ring_b[sl][st + u][lane];
    }
  };
  auto S = [&](const float2* da, const float2* db) {
    #pragma unroll
    for (int u = 0; u < 8; ++u) {
      float2 va = da[u], vb = db[u];
      // row 0
      float z1 = fmaf(hr2.x, va.x, va.y);
      float z2 = fmaf(hi2.x, va.x, va.y);
      float q1 = z1 + MAGIC_F;                   // RNE at 2^-12 grid => floor
      float q2 = z2 - MAGIC_F;
      float f0 = q1 + q2;                        // exact: magics cancel
      // row 1
      float y1 = fmaf(hr2.y, vb.x, vb.y);
      float y2 = fmaf(hi2.y, vb.x, vb.y);
      float p1 = y1 + MAGIC_F;
      float p2 = y2 - MAGIC_F;
      float f1 = p1 + p2;
      hr2.x = __builtin_amdgcn_cosf(f0);
      hi2.x = __builtin_amdgcn_sinf(f0);
      hr2.y = __builtin_amdgcn_cosf(f1);
      hi2.y = __builtin_amdgcn_sinf(f1);
    }
  };

  // ---- pipeline fill: loaders stage chunks 0 and 1 ----
  if (wave > 0) { stage(0, 0); stage(1, 1); }
  __syncthreads();

  float2 Aa[8], Ab[8], Ba[8], Bb[8];
  if (wave == 0) P(0, Aa, Ab);

  for (int c = 0; c < NCHUNK; ++c) {
    if (wave > 0) {
      if (c + 2 < NCHUNK) stage(c + 2, (c + 2) & 3);
    } else {
      const int g0 = c * 4;
      P(g0 + 1, Ba, Bb); S(Aa, Ab);
      P(g0 + 2, Aa, Ab); S(Ba, Bb);
      P(g0 + 3, Ba, Bb); S(Aa, Ab);
      P(g0 + 4, Aa, Ab); S(Ba, Bb);    // cross-chunk prefetch
    }
    __syncthreads();
  }

  // ---- projection: out[row, j] = sum_k h[row][k] * pw[j, k] + pb[j] ----
  if (wave == 0) {
    lds_h[0][lane]           = hr2.x;
    lds_h[0][D_MODEL + lane] = hi2.x;
    lds_h[1][lane]           = hr2.y;
    lds_h[1][D_MODEL + lane] = hi2.y;
  }
  __syncthreads();
  {
    int r = tid >> 7, j = tid & 127;
    const float4* wrow = (const float4*)(pw + j * NSIG);
    float acc = pb[j];
    #pragma unroll
    for (int k = 0; k < NSIG / 4; ++k) {
      float4 wvv = wrow[k];
      float4 hv  = *(const float4*)&lds_h[r][k * 4];
      acc = fmaf(hv.x, wvv.x, acc);
      acc = fmaf(hv.y, wvv.y, acc);
      acc = fmaf(hv.z, wvv.z, acc);
      acc = fmaf(hv.w, wvv.w, acc);
    }
    out[(2 * blk + r) * NSIG + j] = acc;
  }
}

extern "C" void kernel_launch(void* const* d_in, const int* in_sizes, int n_in,
                              void* d_out, int out_size, void* d_ws, size_t ws_size,
                              hipStream_t stream) {
  const int*   ids = (const int*)d_in[0];
  const float* emb = (const float*)d_in[1];
  const float* pw  = (const float*)d_in[2];
  const float* pb  = (const float*)d_in[3];
  float*       out = (float*)d_out;

  rin_scan_kernel<<<dim3(BATCH / 2), dim3(256), 0, stream>>>(ids, emb, pw, pb, out);
}

// Round 8
// 165.448 us; speedup vs baseline: 1.8151x; 1.8151x over previous
//
#include <hip/hip_runtime.h>

#define D_MODEL 64
#define SEQ     4096
#define BATCH   256
#define NSIG    128
#define CSTEP   64
#define NCHUNK  (SEQ / CSTEP)   // 64
#define NGRP    (SEQ / 8)       // 512 groups of 8 steps

constexpr float PHI_F     = 1.61803398874989484820f;
constexpr float TWO_PI_F  = 6.28318530717958647692f;
constexpr float INV2PI_F  = 0.15915494309189533577f;
constexpr float MAGIC_F   = 3072.0f;            // quantizes at ulp 2^-12 = 1 LUT bin
constexpr float FLOORB_F  = 0.0001220703125f;   // 2^-13: RNE(y - 2^-13) at 2^-12 grid == floor

// One block (512 threads = 8 waves) per batch row (256 blocks).
// wave 0: serial 4096-step scan (lane = dim). Chain: fma -> +-3072 magic
//   quantize -> add -> cos/sin (3 VALU links + trans latency).
// waves 1-7: loaders — each handles ~10 of the 64 steps per chunk, so all
//   gather loads for a stage issue in ONE latency round (R5-R7 were bound by
//   3 loader waves x 22 units splitting into ~5 rounds, T_stage ~4.5k cyc).
// ids pre-staged in LDS; 4-slot ring, loaders 3 chunks ahead; float2 plane
// layout (8 B lane stride — measured conflict-free).
__global__ __launch_bounds__(512, 1)
void rin_scan_kernel(const int* __restrict__ ids,
                     const float* __restrict__ emb,   // (50257, 128) f32
                     const float* __restrict__ pw,    // (128, 128) f32
                     const float* __restrict__ pb,    // (128,) f32
                     float* __restrict__ out)         // (256, 128) f32
{
  __shared__ int    lds_ids[SEQ];                // 16 KB
  __shared__ float2 ring[4][CSTEP][D_MODEL];     // 128 KB: (r4, C) per [slot][step][lane]
  __shared__ float  lds_h[2 * D_MODEL];

  const int tid  = threadIdx.x;
  const int wave = tid >> 6;
  const int lane = tid & 63;
  const int b    = blockIdx.x;

  // ---- stage token ids (coalesced int4, all 512 threads) ----
  {
    const int4* src = (const int4*)(ids + b * SEQ);
    int4* dst = (int4*)lds_ids;
    #pragma unroll
    for (int i = 0; i < SEQ / 4 / 512; ++i)      // 2 iters
      dst[tid + i * 512] = src[tid + i * 512];
  }
  __syncthreads();

  float hr = 0.0f, hi = 0.0f;

  // ---- loader: stage chunk c into ring slot s (waves 1-7, ~10 units each) ----
  auto stage = [&](int c, int s) {
    float wv[10], bv[10];
    #pragma unroll
    for (int k = 0; k < 10; ++k) {
      int i = 7 * k + (wave - 1); i = (i < CSTEP) ? i : (CSTEP - 1);
      int t = c * CSTEP + i;
      int id = lds_ids[t];                       // wave-uniform
      const float* row = emb + (size_t)id * (2 * D_MODEL);
      wv[k] = row[lane];
      bv[k] = row[D_MODEL + lane];
    }
    #pragma unroll
    for (int k = 0; k < 10; ++k) {
      int i = 7 * k + (wave - 1); i = (i < CSTEP) ? i : (CSTEP - 1);
      int t = c * CSTEP + i;
      float pf  = (float)t * PHI_F;
      float n   = floorf(pf * INV2PI_F);
      float tp  = fmaf(-n, TWO_PI_F, pf);        // fmod(t*PHI, 2pi)
      float tpr = tp * INV2PI_F;                 // revolutions
      float r4  = __builtin_amdgcn_rcpf(1.0f + fabsf(wv[k])) * INV2PI_F;
      float C   = fmaf(bv[k], INV2PI_F, tpr) - FLOORB_F;
      ring[s][i][lane] = make_float2(r4, C);     // duplicate writes at clamp: same data
    }
  };

  // ---- compute helpers (wave 0); g = global group index 0..NGRP-1 ----
  auto P = [&](int g, float2* dst) {
    int gg = (g < NGRP) ? g : (NGRP - 1);
    int sl = (gg >> 3) & 3, st = (gg & 7) * 8;
    #pragma unroll
    for (int u = 0; u < 8; ++u)
      dst[u] = ring[sl][st + u][lane];
  };
  auto S = [&](const float2* F) {
    #pragma unroll
    for (int u = 0; u < 8; ++u) {
      float2 v = F[u];
      float z1 = fmaf(hr, v.x, v.y);
      float z2 = fmaf(hi, v.x, v.y);
      float q1 = z1 + MAGIC_F;                   // RNE at 2^-12 grid => floor (bias folded in C)
      float q2 = z2 - MAGIC_F;
      float f  = q1 + q2;                        // exact: magics cancel, |f| < 4
      hr = __builtin_amdgcn_cosf(f);             // HW range reduction covers |f| <= 4
      hi = __builtin_amdgcn_sinf(f);
    }
  };

  // ---- pipeline fill: loaders stage chunks 0..2 ----
  if (wave > 0) { stage(0, 0); stage(1, 1); stage(2, 2); }
  __syncthreads();

  float2 A[8], B[8];
  if (wave == 0) P(0, A);

  for (int c = 0; c < NCHUNK; ++c) {
    if (wave > 0) {
      if (c + 3 < NCHUNK) stage(c + 3, (c + 3) & 3);
    } else {
      const int g0 = c * 8;
      P(g0 + 1, B); S(A);
      P(g0 + 2, A); S(B);
      P(g0 + 3, B); S(A);
      P(g0 + 4, A); S(B);
      P(g0 + 5, B); S(A);
      P(g0 + 6, A); S(B);
      P(g0 + 7, B); S(A);
      P(g0 + 8, A); S(B);    // cross-chunk prefetch (slot (c+1)&3, staged 2 chunks ago)
    }
    __syncthreads();
  }

  // ---- projection: out[b, j] = sum_k h[k] * pw[j, k] + pb[j] ----
  if (wave == 0) {
    lds_h[lane] = hr;
    lds_h[D_MODEL + lane] = hi;
  }
  __syncthreads();
  if (tid < NSIG) {
    int j = tid;
    const float4* wrow = (const float4*)(pw + j * NSIG);
    float acc = pb[j];
    #pragma unroll
    for (int k = 0; k < NSIG / 4; ++k) {
      float4 wvv = wrow[k];
      float4 hv  = *(const float4*)&lds_h[k * 4];
      acc = fmaf(hv.x, wvv.x, acc);
      acc = fmaf(hv.y, wvv.y, acc);
      acc = fmaf(hv.z, wvv.z, acc);
      acc = fmaf(hv.w, wvv.w, acc);
    }
    out[b * NSIG + j] = acc;
  }
}

extern "C" void kernel_launch(void* const* d_in, const int* in_sizes, int n_in,
                              void* d_out, int out_size, void* d_ws, size_t ws_size,
                              hipStream_t stream) {
  const int*   ids = (const int*)d_in[0];
  const float* emb = (const float*)d_in[1];
  const float* pw  = (const float*)d_in[2];
  const float* pb  = (const float*)d_in[3];
  float*       out = (float*)d_out;

  rin_scan_kernel<<<dim3(BATCH), dim3(512), 0, stream>>>(ids, emb, pw, pb, out);
}